// Round 1
// baseline (454.870 us; speedup 1.0000x reference)
//
#include <hip/hip_runtime.h>
#include <math.h>

#define N_NODE 100000
#define N_EDGE 1600000
#define D_FEAT 64
#define DEPTH  3
#define OUT_STRIDE ((DEPTH + 1) * D_FEAT)   // 256 floats per node row

#define SCAN_BS 1024
#define N_SCAN_BLOCKS ((N_NODE + SCAN_BS - 1) / SCAN_BS)   // 98

// XCD-range partitioning: 8 XCDs, round-robin blockIdx -> XCD.
// Range j (nodes [j*12500, (j+1)*12500)) is processed only by blocks with
// blockIdx % 8 == j, i.e. only by XCD j -> its csr/cursor/packed slice stays
// resident in that XCD's private 4MB L2, so partial-line writes merge.
#define N_RANGE 8
#define RANGE_NODES (N_NODE / N_RANGE)      // 12500
#define EDGE_BS 512
#define EDGE_CHUNKS ((N_EDGE + EDGE_BS - 1) / EDGE_BS)     // 3125

// fixed-point scale for degree accumulation (ea in [0,1), max degree ~45)
#define DEG_SCALE 33554432.0f           // 2^25
#define DEG_MASK  0xFFFFFFFFFFULL       // low 40 bits
#define CNT_SHIFT 40

__device__ __forceinline__ unsigned int bf16_rne(float f) {
    unsigned int u = __float_as_uint(f);
    return (u + 0x7FFFu + ((u >> 16) & 1u)) >> 16;
}

// ---------------------------------------------------------------------------
// 1. one packed 64-bit atomic per edge: count (bits 40+) | fixed-point deg.
//    XCD-partitioned: block (rng, chunk) commits only rows in range rng.
__global__ void deg_cnt_kernel(const int* __restrict__ ei,
                               const float* __restrict__ ea,
                               unsigned long long* __restrict__ packed) {
    int rng = blockIdx.x & (N_RANGE - 1);
    int e   = (blockIdx.x >> 3) * EDGE_BS + threadIdx.x;
    if (e >= N_EDGE) return;
    int r  = ei[e];
    int lo = rng * RANGE_NODES;
    if (r >= lo && r < lo + RANGE_NODES) {
        unsigned long long v = (1ULL << CNT_SHIFT) |
                               (unsigned long long)(ea[e] * DEG_SCALE + 0.5f);
        atomicAdd(&packed[r], v);
    }
}

// ---------------------------------------------------------------------------
// 2a. per-block exclusive scan of counts -> row_ptr, block totals -> bsum.
//     Fused unpack: also writes dinv[i].
__global__ void scan1_kernel(const unsigned long long* __restrict__ packed,
                             float* __restrict__ dinv,
                             int* __restrict__ row_ptr,
                             int* __restrict__ bsum) {
    __shared__ int tmp[SCAN_BS];
    int i = blockIdx.x * SCAN_BS + threadIdx.x;
    int v = 0;
    if (i < N_NODE) {
        unsigned long long p = packed[i];
        v = (int)(p >> CNT_SHIFT);
        float d = (float)(p & DEG_MASK) * (1.0f / DEG_SCALE);
        dinv[i] = (d > 0.0f) ? rsqrtf(d) : 0.0f;
    }
    tmp[threadIdx.x] = v;
    __syncthreads();
    for (int off = 1; off < SCAN_BS; off <<= 1) {
        int t = (threadIdx.x >= off) ? tmp[threadIdx.x - off] : 0;
        __syncthreads();
        tmp[threadIdx.x] += t;
        __syncthreads();
    }
    if (i < N_NODE) row_ptr[i] = tmp[threadIdx.x] - v;  // exclusive
    if (threadIdx.x == SCAN_BS - 1) bsum[blockIdx.x] = tmp[SCAN_BS - 1];
}

// 2b. exclusive scan of the 98 block sums; also a[L] = tanh(alphas[L])
__global__ void scan2_kernel(int* __restrict__ bsum,
                             const float* __restrict__ alphas,
                             float* __restrict__ a_vals) {
    __shared__ int tmp[128];
    int v = (threadIdx.x < N_SCAN_BLOCKS) ? bsum[threadIdx.x] : 0;
    tmp[threadIdx.x] = v;
    __syncthreads();
    for (int off = 1; off < 128; off <<= 1) {
        int t = (threadIdx.x >= off) ? tmp[threadIdx.x - off] : 0;
        __syncthreads();
        tmp[threadIdx.x] += t;
        __syncthreads();
    }
    if (threadIdx.x < N_SCAN_BLOCKS) bsum[threadIdx.x] = tmp[threadIdx.x] - v;
    if (threadIdx.x < DEPTH + 1) a_vals[threadIdx.x] = tanhf(alphas[threadIdx.x]);
}

// 2c. add block offsets; init cursor = row_ptr
__global__ void scan3_kernel(int* __restrict__ row_ptr,
                             const int* __restrict__ bsum,
                             int* __restrict__ cursor) {
    int i = blockIdx.x * blockDim.x + threadIdx.x;
    if (i < N_NODE) {
        int v = row_ptr[i] + bsum[i >> 10];
        row_ptr[i] = v;
        cursor[i]  = v;
    }
}

// ---------------------------------------------------------------------------
// 3. scatter edges into packed CSR: csr[pos] = {col, bits(dinv_r*w*dinv_c)}.
//    XCD-partitioned like deg_cnt: each XCD writes only its 1.6MB csr slice,
//    so the 8B partial-line writes merge in its L2 instead of 8x amplifying.
__global__ void scatter_kernel(const int* __restrict__ ei,
                               const float* __restrict__ ea,
                               const float* __restrict__ dinv,
                               int* __restrict__ cursor,
                               int2* __restrict__ csr) {
    int rng = blockIdx.x & (N_RANGE - 1);
    int e   = (blockIdx.x >> 3) * EDGE_BS + threadIdx.x;
    if (e >= N_EDGE) return;
    int r  = ei[e];
    int lo = rng * RANGE_NODES;
    if (r < lo || r >= lo + RANGE_NODES) return;
    int c = ei[N_EDGE + e];
    int pos = atomicAdd(&cursor[r], 1);
    float v = dinv[r] * ea[e] * dinv[c];
    csr[pos] = make_int2(c, __float_as_int(v));
}

// ---------------------------------------------------------------------------
// 4. out[n, 0, d] = x[n, d]; optionally also bf16 shadow hb0[n*64+d]
__global__ void init_out_kernel(const float* __restrict__ x,
                                float* __restrict__ out,
                                unsigned short* __restrict__ hb0,
                                int write_hb) {
    int i = blockIdx.x * blockDim.x + threadIdx.x;
    if (i < N_NODE * D_FEAT) {
        int n = i >> 6;
        int d = i & 63;
        float v = x[i];
        out[(size_t)n * OUT_STRIDE + d] = v;
        if (write_hb) hb0[i] = (unsigned short)bf16_rne(v);
    }
}

// ---------------------------------------------------------------------------
// 5a. gather SpMM, bf16 source: wave = node; 4 edge-groups x 16 lanes x 4 feats
__global__ void spmm_bf16_kernel(const int* __restrict__ row_ptr,
                                 const int* __restrict__ row_end,
                                 const int2* __restrict__ csr,
                                 const float* __restrict__ a_vals,
                                 const unsigned short* __restrict__ hsrc,
                                 unsigned short* __restrict__ hdst,
                                 float* __restrict__ out,
                                 int L, int write_hdst) {
    int node = blockIdx.x * (blockDim.x >> 6) + (threadIdx.x >> 6);
    int lane = threadIdx.x & 63;
    if (node >= N_NODE) return;
    int beg = row_ptr[node];
    int end = row_end[node];
    int g = lane >> 4;        // edge subgroup 0..3
    int q = lane & 15;        // 4-feature slot

    float4 acc = make_float4(0.0f, 0.0f, 0.0f, 0.0f);

    for (int chunk = beg; chunk < end; chunk += 64) {
        int idx = chunk + lane;
        int2 pv = (idx < end) ? csr[idx] : make_int2(0, 0);
        int navail = end - chunk;
        if (navail > 64) navail = 64;
        for (int t = 0; t < navail; t += 4) {
            int sub = t + g;
            int   cc = __shfl(pv.x, sub);
            float vv = __int_as_float(__shfl(pv.y, sub));
            bool valid = (sub < navail);
            int   c_safe = valid ? cc : 0;
            float v_safe = valid ? vv : 0.0f;
            uint2 hv = *(const uint2*)&hsrc[(size_t)c_safe * D_FEAT + (q << 2)];
            float h0 = __uint_as_float((hv.x & 0xFFFFu) << 16);
            float h1 = __uint_as_float(hv.x & 0xFFFF0000u);
            float h2 = __uint_as_float((hv.y & 0xFFFFu) << 16);
            float h3 = __uint_as_float(hv.y & 0xFFFF0000u);
            acc.x += v_safe * h0;
            acc.y += v_safe * h1;
            acc.z += v_safe * h2;
            acc.w += v_safe * h3;
        }
    }

    acc.x += __shfl_down(acc.x, 32);
    acc.y += __shfl_down(acc.y, 32);
    acc.z += __shfl_down(acc.z, 32);
    acc.w += __shfl_down(acc.w, 32);
    acc.x += __shfl_down(acc.x, 16);
    acc.y += __shfl_down(acc.y, 16);
    acc.z += __shfl_down(acc.z, 16);
    acc.w += __shfl_down(acc.w, 16);

    if (g == 0) {
        float aL = a_vals[L];
        float4 r = make_float4(aL * acc.x, aL * acc.y, aL * acc.z, aL * acc.w);
        *(float4*)&out[(size_t)node * OUT_STRIDE + L * D_FEAT + (q << 2)] = r;
        if (write_hdst) {
            uint2 o;
            o.x = bf16_rne(r.x) | (bf16_rne(r.y) << 16);
            o.y = bf16_rne(r.z) | (bf16_rne(r.w) << 16);
            *(uint2*)&hdst[(size_t)node * D_FEAT + (q << 2)] = o;
        }
    }
}

// 5b. fallback fp32-source gather (used only if ws too small for shadows)
__global__ void spmm_f32_kernel(const int* __restrict__ row_ptr,
                                const int* __restrict__ row_end,
                                const int2* __restrict__ csr,
                                const float* __restrict__ a_vals,
                                float* __restrict__ out,
                                int L) {
    int node = blockIdx.x * (blockDim.x >> 6) + (threadIdx.x >> 6);
    int lane = threadIdx.x & 63;
    if (node >= N_NODE) return;
    int beg = row_ptr[node];
    int end = row_end[node];
    int g = lane >> 4;
    int q = lane & 15;
    int src_base = (L - 1) * D_FEAT + (q << 2);

    float4 acc = make_float4(0.0f, 0.0f, 0.0f, 0.0f);
    for (int chunk = beg; chunk < end; chunk += 64) {
        int idx = chunk + lane;
        int2 pv = (idx < end) ? csr[idx] : make_int2(0, 0);
        int navail = end - chunk;
        if (navail > 64) navail = 64;
        for (int t = 0; t < navail; t += 4) {
            int sub = t + g;
            int   cc = __shfl(pv.x, sub);
            float vv = __int_as_float(__shfl(pv.y, sub));
            bool valid = (sub < navail);
            int   c_safe = valid ? cc : 0;
            float v_safe = valid ? vv : 0.0f;
            const float4 hv =
                *(const float4*)&out[(size_t)c_safe * OUT_STRIDE + src_base];
            acc.x += v_safe * hv.x;
            acc.y += v_safe * hv.y;
            acc.z += v_safe * hv.z;
            acc.w += v_safe * hv.w;
        }
    }
    acc.x += __shfl_down(acc.x, 32);
    acc.y += __shfl_down(acc.y, 32);
    acc.z += __shfl_down(acc.z, 32);
    acc.w += __shfl_down(acc.w, 32);
    acc.x += __shfl_down(acc.x, 16);
    acc.y += __shfl_down(acc.y, 16);
    acc.z += __shfl_down(acc.z, 16);
    acc.w += __shfl_down(acc.w, 16);
    if (g == 0) {
        float aL = a_vals[L];
        float4 r = make_float4(aL * acc.x, aL * acc.y, aL * acc.z, aL * acc.w);
        *(float4*)&out[(size_t)node * OUT_STRIDE + L * D_FEAT + (q << 2)] = r;
    }
}

// ---------------------------------------------------------------------------
extern "C" void kernel_launch(void* const* d_in, const int* in_sizes, int n_in,
                              void* d_out, int out_size, void* d_ws, size_t ws_size,
                              hipStream_t stream) {
    const float* x      = (const float*)d_in[0];
    const int*   ei     = (const int*)d_in[1];   // [2, E] int32
    const float* ea     = (const float*)d_in[2];
    const float* alphas = (const float*)d_in[3];
    float*       out    = (float*)d_out;

    // workspace layout
    unsigned long long* packed = (unsigned long long*)d_ws;   // N (800 KB)
    int2*  csr     = (int2*)(packed + N_NODE);                // E (12.8 MB)
    float* dinv    = (float*)(csr + N_EDGE);                  // N
    int*   row_ptr = (int*)(dinv + N_NODE);                   // N
    int*   cursor  = row_ptr + N_NODE;                        // N
    int*   bsum    = cursor + N_NODE;                         // 128
    float* a_vals  = (float*)(bsum + 128);                    // 4
    unsigned short* hb0 = (unsigned short*)(a_vals + 4);      // N*64 bf16
    unsigned short* hb1 = hb0 + (size_t)N_NODE * D_FEAT;      // N*64 bf16

    size_t base_bytes = (size_t)((char*)hb0 - (char*)d_ws);
    size_t need_bf16  = base_bytes + 2 * (size_t)N_NODE * D_FEAT * sizeof(unsigned short);
    int use_bf16 = (ws_size >= need_bf16) ? 1 : 0;   // constant across calls

    hipMemsetAsync(packed, 0, N_NODE * sizeof(unsigned long long), stream);

    int edge_grid = N_RANGE * EDGE_CHUNKS;   // 8 range-copies, XCD-pinned
    deg_cnt_kernel<<<edge_grid, EDGE_BS, 0, stream>>>(ei, ea, packed);
    scan1_kernel<<<N_SCAN_BLOCKS, SCAN_BS, 0, stream>>>(packed, dinv, row_ptr,
                                                        bsum);
    scan2_kernel<<<1, 128, 0, stream>>>(bsum, alphas, a_vals);
    scan3_kernel<<<(N_NODE + 255) / 256, 256, 0, stream>>>(row_ptr, bsum, cursor);
    scatter_kernel<<<edge_grid, EDGE_BS, 0, stream>>>(ei, ea, dinv, cursor, csr);
    init_out_kernel<<<(N_NODE * D_FEAT + 255) / 256, 256, 0, stream>>>(
        x, out, hb0, use_bf16);

    int nodes_per_block = 256 / 64;
    int spmm_blocks = (N_NODE + nodes_per_block - 1) / nodes_per_block;
    if (use_bf16) {
        // L=1: src hb0 -> dst hb1 ; L=2: src hb1 -> dst hb0 ; L=3: src hb0, no dst
        spmm_bf16_kernel<<<spmm_blocks, 256, 0, stream>>>(row_ptr, cursor, csr,
                                                          a_vals, hb0, hb1, out, 1, 1);
        spmm_bf16_kernel<<<spmm_blocks, 256, 0, stream>>>(row_ptr, cursor, csr,
                                                          a_vals, hb1, hb0, out, 2, 1);
        spmm_bf16_kernel<<<spmm_blocks, 256, 0, stream>>>(row_ptr, cursor, csr,
                                                          a_vals, hb0, hb1, out, 3, 0);
    } else {
        for (int L = 1; L <= DEPTH; ++L) {
            spmm_f32_kernel<<<spmm_blocks, 256, 0, stream>>>(row_ptr, cursor, csr,
                                                             a_vals, out, L);
        }
    }
}

// Round 2
// 347.013 us; speedup vs baseline: 1.3108x; 1.3108x over previous
//
#include <hip/hip_runtime.h>
#include <math.h>

#define N_NODE 100000
#define N_EDGE 1600000
#define D_FEAT 64
#define DEPTH  3
#define OUT_STRIDE ((DEPTH + 1) * D_FEAT)   // 256 floats per node row

// ---- bucketed CSR build ----------------------------------------------------
#define NB  256                      // coarse buckets
#define RPB 391                      // rows per bucket: 256*391 = 100096 >= N
#define CAP 8192                     // per-bucket edge capacity (mean 6250, +24 sigma)
#define S1_BS 512
#define S1_CHUNK 8192                // edges per stage1 block
#define S1_BLOCKS ((N_EDGE + S1_CHUNK - 1) / S1_CHUNK)   // 196

// fixed-point scale for weighted-degree accumulation (ea in [0,1), deg < 128)
#define DEG_SCALE 33554432.0f        // 2^25

__device__ __forceinline__ unsigned int bf16_rne(float f) {
    unsigned int u = __float_as_uint(f);
    return (u + 0x7FFFu + ((u >> 16) & 1u)) >> 16;
}

// ---------------------------------------------------------------------------
// 1. multisplit edges into NB buckets. Per block: LDS histogram -> one global
//    atomic per (block,bucket) reserving a contiguous segment -> segment
//    writes are ~32 edges (256 B) contiguous => ~1.25x line amplification,
//    no dependence on cache residency.
__global__ __launch_bounds__(S1_BS) void stage1_bucket(
        const int* __restrict__ ei, const float* __restrict__ ea,
        int* __restrict__ bucket_cursor, int2* __restrict__ bucket) {
    __shared__ int hist[NB];
    __shared__ int segb[NB];
    int tid = threadIdx.x;
    int e0 = blockIdx.x * S1_CHUNK;

    for (int i = tid; i < NB; i += S1_BS) hist[i] = 0;
    __syncthreads();

    for (int k = 0; k < S1_CHUNK; k += S1_BS) {
        int e = e0 + k + tid;
        if (e < N_EDGE) {
            int r = ei[e];
            atomicAdd(&hist[r / RPB], 1);
        }
    }
    __syncthreads();

    for (int i = tid; i < NB; i += S1_BS) {
        int h = hist[i];
        segb[i] = (h > 0) ? atomicAdd(&bucket_cursor[i], h) : 0;
        hist[i] = 0;
    }
    __syncthreads();

    for (int k = 0; k < S1_CHUNK; k += S1_BS) {
        int e = e0 + k + tid;
        if (e < N_EDGE) {
            int r  = ei[e];               // L1-hot (read in pass 1)
            int b  = r / RPB;
            int rl = r - b * RPB;         // < 391, 9 bits
            int c  = ei[N_EDGE + e];      // < 100000, 17 bits
            float w = ea[e];
            int lofs = atomicAdd(&hist[b], 1);
            int pos  = segb[b] + lofs;
            if (pos < CAP)
                bucket[(size_t)b * CAP + pos] =
                    make_int2((rl << 17) | c, __float_as_int(w));
        }
    }
}

// ---------------------------------------------------------------------------
// 2. exclusive scan of NB bucket counts -> CSR bucket bases; a[L]=tanh(alpha)
__global__ void bucket_scan_kernel(const int* __restrict__ bucket_cursor,
                                   int* __restrict__ bucket_base,
                                   const float* __restrict__ alphas,
                                   float* __restrict__ a_vals) {
    __shared__ int sc[NB];
    int tid = threadIdx.x;               // 256 threads
    int v = bucket_cursor[tid];
    sc[tid] = v;
    __syncthreads();
    for (int off = 1; off < NB; off <<= 1) {
        int t = (tid >= off) ? sc[tid - off] : 0;
        __syncthreads();
        sc[tid] += t;
        __syncthreads();
    }
    bucket_base[tid] = sc[tid] - v;      // exclusive
    if (tid < DEPTH + 1) a_vals[tid] = tanhf(alphas[tid]);
}

// ---------------------------------------------------------------------------
// 3. per-bucket: row counts + fixed-point weighted degree (LDS atomics),
//    block scan -> row_ptr/row_end/dinv (all coalesced writes).
__global__ __launch_bounds__(1024) void stage2a_rows(
        const int2* __restrict__ bucket, const int* __restrict__ bucket_cnt,
        const int* __restrict__ bucket_base,
        int* __restrict__ row_ptr, int* __restrict__ row_end,
        float* __restrict__ dinv) {
    __shared__ int          rcnt[RPB];
    __shared__ unsigned int wdeg[RPB];
    __shared__ int          sc[512];
    int b = blockIdx.x, tid = threadIdx.x;

    for (int i = tid; i < RPB; i += 1024) { rcnt[i] = 0; wdeg[i] = 0u; }
    __syncthreads();

    int cnt = bucket_cnt[b];
    const int2* src = bucket + (size_t)b * CAP;
    for (int i = tid; i < cnt; i += 1024) {
        int2 e = src[i];
        int rl = e.x >> 17;
        float w = __int_as_float(e.y);
        atomicAdd(&rcnt[rl], 1);
        atomicAdd(&wdeg[rl], (unsigned int)(w * DEG_SCALE + 0.5f));
    }
    __syncthreads();

    // inclusive scan over 512 (RPB padded)
    int v = 0;
    if (tid < 512) {
        v = (tid < RPB) ? rcnt[tid] : 0;
        sc[tid] = v;
    }
    __syncthreads();
    for (int off = 1; off < 512; off <<= 1) {
        int t = 0;
        if (tid < 512 && tid >= off) t = sc[tid - off];
        __syncthreads();
        if (tid < 512) sc[tid] += t;
        __syncthreads();
    }

    if (tid < RPB) {
        int row = b * RPB + tid;
        if (row < N_NODE) {
            int base = bucket_base[b] + sc[tid] - v;   // exclusive
            row_ptr[row] = base;
            row_end[row] = base + rcnt[tid];
            float d = (float)wdeg[tid] * (1.0f / DEG_SCALE);
            dinv[row] = (d > 0.0f) ? rsqrtf(d) : 0.0f;
        }
    }
}

// ---------------------------------------------------------------------------
// 4. per-bucket: place edges at exact CSR offsets in a 64KB LDS staging
//    buffer (LDS atomics on per-row cursors), compute val, then stream the
//    bucket's CSR region out fully coalesced.
__global__ __launch_bounds__(1024) void stage2b_place(
        const int2* __restrict__ bucket, const int* __restrict__ bucket_cnt,
        const int* __restrict__ bucket_base, const int* __restrict__ row_ptr,
        const float* __restrict__ dinv, int2* __restrict__ csr) {
    __shared__ int   lcur[RPB];
    __shared__ float dinv_l[RPB];
    __shared__ int2  staged[CAP];        // 64 KB
    int b = blockIdx.x, tid = threadIdx.x;
    int base_b = bucket_base[b];
    int row0 = b * RPB;

    for (int i = tid; i < RPB; i += 1024) {
        int row = row0 + i;
        if (row < N_NODE) {
            lcur[i]   = row_ptr[row] - base_b;   // local exclusive offset
            dinv_l[i] = dinv[row];
        } else {
            lcur[i] = 0; dinv_l[i] = 0.0f;
        }
    }
    __syncthreads();

    int cnt = bucket_cnt[b];
    const int2* src = bucket + (size_t)b * CAP;
    for (int i = tid; i < cnt; i += 1024) {
        int2 e = src[i];
        int rl = e.x >> 17;
        int c  = e.x & 0x1FFFF;
        float w = __int_as_float(e.y);
        int pos = atomicAdd(&lcur[rl], 1);
        float val = dinv_l[rl] * w * dinv[c];    // same op order as before
        staged[pos] = make_int2(c, __float_as_int(val));
    }
    __syncthreads();

    for (int i = tid; i < cnt; i += 1024) csr[base_b + i] = staged[i];
}

// ---------------------------------------------------------------------------
// 5. out[n, 0, d] = x[n, d]; optionally also bf16 shadow hb0[n*64+d]
__global__ void init_out_kernel(const float* __restrict__ x,
                                float* __restrict__ out,
                                unsigned short* __restrict__ hb0,
                                int write_hb) {
    int i = blockIdx.x * blockDim.x + threadIdx.x;
    if (i < N_NODE * D_FEAT) {
        int n = i >> 6;
        int d = i & 63;
        float v = x[i];
        out[(size_t)n * OUT_STRIDE + d] = v;
        if (write_hb) hb0[i] = (unsigned short)bf16_rne(v);
    }
}

// ---------------------------------------------------------------------------
// 6a. gather SpMM, bf16 source: wave = node; 4 edge-groups x 16 lanes x 4 feats
__global__ void spmm_bf16_kernel(const int* __restrict__ row_ptr,
                                 const int* __restrict__ row_end,
                                 const int2* __restrict__ csr,
                                 const float* __restrict__ a_vals,
                                 const unsigned short* __restrict__ hsrc,
                                 unsigned short* __restrict__ hdst,
                                 float* __restrict__ out,
                                 int L, int write_hdst) {
    int node = blockIdx.x * (blockDim.x >> 6) + (threadIdx.x >> 6);
    int lane = threadIdx.x & 63;
    if (node >= N_NODE) return;
    int beg = row_ptr[node];
    int end = row_end[node];
    int g = lane >> 4;        // edge subgroup 0..3
    int q = lane & 15;        // 4-feature slot

    float4 acc = make_float4(0.0f, 0.0f, 0.0f, 0.0f);

    for (int chunk = beg; chunk < end; chunk += 64) {
        int idx = chunk + lane;
        int2 pv = (idx < end) ? csr[idx] : make_int2(0, 0);
        int navail = end - chunk;
        if (navail > 64) navail = 64;
        for (int t = 0; t < navail; t += 4) {
            int sub = t + g;
            int   cc = __shfl(pv.x, sub);
            float vv = __int_as_float(__shfl(pv.y, sub));
            bool valid = (sub < navail);
            int   c_safe = valid ? cc : 0;
            float v_safe = valid ? vv : 0.0f;
            uint2 hv = *(const uint2*)&hsrc[(size_t)c_safe * D_FEAT + (q << 2)];
            float h0 = __uint_as_float((hv.x & 0xFFFFu) << 16);
            float h1 = __uint_as_float(hv.x & 0xFFFF0000u);
            float h2 = __uint_as_float((hv.y & 0xFFFFu) << 16);
            float h3 = __uint_as_float(hv.y & 0xFFFF0000u);
            acc.x += v_safe * h0;
            acc.y += v_safe * h1;
            acc.z += v_safe * h2;
            acc.w += v_safe * h3;
        }
    }

    acc.x += __shfl_down(acc.x, 32);
    acc.y += __shfl_down(acc.y, 32);
    acc.z += __shfl_down(acc.z, 32);
    acc.w += __shfl_down(acc.w, 32);
    acc.x += __shfl_down(acc.x, 16);
    acc.y += __shfl_down(acc.y, 16);
    acc.z += __shfl_down(acc.z, 16);
    acc.w += __shfl_down(acc.w, 16);

    if (g == 0) {
        float aL = a_vals[L];
        float4 r = make_float4(aL * acc.x, aL * acc.y, aL * acc.z, aL * acc.w);
        *(float4*)&out[(size_t)node * OUT_STRIDE + L * D_FEAT + (q << 2)] = r;
        if (write_hdst) {
            uint2 o;
            o.x = bf16_rne(r.x) | (bf16_rne(r.y) << 16);
            o.y = bf16_rne(r.z) | (bf16_rne(r.w) << 16);
            *(uint2*)&hdst[(size_t)node * D_FEAT + (q << 2)] = o;
        }
    }
}

// 6b. fallback fp32-source gather (used only if ws too small for shadows)
__global__ void spmm_f32_kernel(const int* __restrict__ row_ptr,
                                const int* __restrict__ row_end,
                                const int2* __restrict__ csr,
                                const float* __restrict__ a_vals,
                                float* __restrict__ out,
                                int L) {
    int node = blockIdx.x * (blockDim.x >> 6) + (threadIdx.x >> 6);
    int lane = threadIdx.x & 63;
    if (node >= N_NODE) return;
    int beg = row_ptr[node];
    int end = row_end[node];
    int g = lane >> 4;
    int q = lane & 15;
    int src_base = (L - 1) * D_FEAT + (q << 2);

    float4 acc = make_float4(0.0f, 0.0f, 0.0f, 0.0f);
    for (int chunk = beg; chunk < end; chunk += 64) {
        int idx = chunk + lane;
        int2 pv = (idx < end) ? csr[idx] : make_int2(0, 0);
        int navail = end - chunk;
        if (navail > 64) navail = 64;
        for (int t = 0; t < navail; t += 4) {
            int sub = t + g;
            int   cc = __shfl(pv.x, sub);
            float vv = __int_as_float(__shfl(pv.y, sub));
            bool valid = (sub < navail);
            int   c_safe = valid ? cc : 0;
            float v_safe = valid ? vv : 0.0f;
            const float4 hv =
                *(const float4*)&out[(size_t)c_safe * OUT_STRIDE + src_base];
            acc.x += v_safe * hv.x;
            acc.y += v_safe * hv.y;
            acc.z += v_safe * hv.z;
            acc.w += v_safe * hv.w;
        }
    }
    acc.x += __shfl_down(acc.x, 32);
    acc.y += __shfl_down(acc.y, 32);
    acc.z += __shfl_down(acc.z, 32);
    acc.w += __shfl_down(acc.w, 32);
    acc.x += __shfl_down(acc.x, 16);
    acc.y += __shfl_down(acc.y, 16);
    acc.z += __shfl_down(acc.z, 16);
    acc.w += __shfl_down(acc.w, 16);
    if (g == 0) {
        float aL = a_vals[L];
        float4 r = make_float4(aL * acc.x, aL * acc.y, aL * acc.z, aL * acc.w);
        *(float4*)&out[(size_t)node * OUT_STRIDE + L * D_FEAT + (q << 2)] = r;
    }
}

// ---------------------------------------------------------------------------
extern "C" void kernel_launch(void* const* d_in, const int* in_sizes, int n_in,
                              void* d_out, int out_size, void* d_ws, size_t ws_size,
                              hipStream_t stream) {
    const float* x      = (const float*)d_in[0];
    const int*   ei     = (const int*)d_in[1];   // [2, E] int32
    const float* ea     = (const float*)d_in[2];
    const float* alphas = (const float*)d_in[3];
    float*       out    = (float*)d_out;

    // workspace layout (bucket store aliases the bf16 shadows: bucket data is
    // dead before init_out runs)
    int2*  csr          = (int2*)d_ws;                       // E     (12.8 MB)
    int*   row_ptr      = (int*)(csr + N_EDGE);              // N
    int*   row_end      = row_ptr + N_NODE;                  // N
    float* dinv         = (float*)(row_end + N_NODE);        // N
    int*   bucket_cursor= (int*)(dinv + N_NODE);             // NB
    int*   bucket_base  = bucket_cursor + NB;                // NB
    float* a_vals       = (float*)(bucket_base + NB);        // 4
    int2*  bucket       = (int2*)(a_vals + 4);               // NB*CAP (16.8 MB)
    unsigned short* hb0 = (unsigned short*)bucket;           // union w/ bucket
    unsigned short* hb1 = hb0 + (size_t)N_NODE * D_FEAT;

    size_t base_bytes = (size_t)((char*)bucket - (char*)d_ws);
    size_t need_bf16  = base_bytes +
        2 * (size_t)N_NODE * D_FEAT * sizeof(unsigned short);   // 39.7 MB
    int use_bf16 = (ws_size >= need_bf16) ? 1 : 0;

    hipMemsetAsync(bucket_cursor, 0, NB * sizeof(int), stream);

    stage1_bucket<<<S1_BLOCKS, S1_BS, 0, stream>>>(ei, ea, bucket_cursor, bucket);
    bucket_scan_kernel<<<1, NB, 0, stream>>>(bucket_cursor, bucket_base,
                                             alphas, a_vals);
    stage2a_rows<<<NB, 1024, 0, stream>>>(bucket, bucket_cursor, bucket_base,
                                          row_ptr, row_end, dinv);
    stage2b_place<<<NB, 1024, 0, stream>>>(bucket, bucket_cursor, bucket_base,
                                           row_ptr, dinv, csr);
    init_out_kernel<<<(N_NODE * D_FEAT + 255) / 256, 256, 0, stream>>>(
        x, out, hb0, use_bf16);

    int nodes_per_block = 256 / 64;
    int spmm_blocks = (N_NODE + nodes_per_block - 1) / nodes_per_block;
    if (use_bf16) {
        // L=1: src hb0 -> dst hb1 ; L=2: src hb1 -> dst hb0 ; L=3: src hb0, no dst
        spmm_bf16_kernel<<<spmm_blocks, 256, 0, stream>>>(row_ptr, row_end, csr,
                                                          a_vals, hb0, hb1, out, 1, 1);
        spmm_bf16_kernel<<<spmm_blocks, 256, 0, stream>>>(row_ptr, row_end, csr,
                                                          a_vals, hb1, hb0, out, 2, 1);
        spmm_bf16_kernel<<<spmm_blocks, 256, 0, stream>>>(row_ptr, row_end, csr,
                                                          a_vals, hb0, hb1, out, 3, 0);
    } else {
        for (int L = 1; L <= DEPTH; ++L) {
            spmm_f32_kernel<<<spmm_blocks, 256, 0, stream>>>(row_ptr, row_end, csr,
                                                             a_vals, out, L);
        }
    }
}

// Round 3
// 331.246 us; speedup vs baseline: 1.3732x; 1.0476x over previous
//
#include <hip/hip_runtime.h>
#include <math.h>

#define N_NODE 100000
#define N_EDGE 1600000
#define D_FEAT 64
#define DEPTH  3
#define OUT_STRIDE ((DEPTH + 1) * D_FEAT)   // 256 floats per node row

// ---- bucketed CSR build ----------------------------------------------------
#define NB  256                      // coarse buckets
#define RPB 391                      // rows per bucket: 256*391 = 100096 >= N
#define CAP 8192                     // per-bucket edge capacity (mean 6250, +24 sigma)
#define S1_BS 512
#define S1_CHUNK 8192                // edges per stage1 block
#define S1_BLOCKS ((N_EDGE + S1_CHUNK - 1) / S1_CHUNK)   // 196

// fixed-point scale for weighted-degree accumulation (ea in [0,1), deg < 128)
#define DEG_SCALE 33554432.0f        // 2^25

__device__ __forceinline__ unsigned int bf16_rne(float f) {
    unsigned int u = __float_as_uint(f);
    return (u + 0x7FFFu + ((u >> 16) & 1u)) >> 16;
}

// ---------------------------------------------------------------------------
// 1. multisplit edges into NB buckets. Per block: LDS histogram -> one global
//    atomic per (block,bucket) reserving a contiguous segment -> segment
//    writes are ~32 edges (256 B) contiguous => ~1.25x line amplification.
__global__ __launch_bounds__(S1_BS) void stage1_bucket(
        const int* __restrict__ ei, const float* __restrict__ ea,
        int* __restrict__ bucket_cursor, int2* __restrict__ bucket) {
    __shared__ int hist[NB];
    __shared__ int segb[NB];
    int tid = threadIdx.x;
    int e0 = blockIdx.x * S1_CHUNK;

    for (int i = tid; i < NB; i += S1_BS) hist[i] = 0;
    __syncthreads();

    for (int k = 0; k < S1_CHUNK; k += S1_BS) {
        int e = e0 + k + tid;
        if (e < N_EDGE) {
            int r = ei[e];
            atomicAdd(&hist[r / RPB], 1);
        }
    }
    __syncthreads();

    for (int i = tid; i < NB; i += S1_BS) {
        int h = hist[i];
        segb[i] = (h > 0) ? atomicAdd(&bucket_cursor[i], h) : 0;
        hist[i] = 0;
    }
    __syncthreads();

    for (int k = 0; k < S1_CHUNK; k += S1_BS) {
        int e = e0 + k + tid;
        if (e < N_EDGE) {
            int r  = ei[e];               // L1-hot (read in pass 1)
            int b  = r / RPB;
            int rl = r - b * RPB;         // < 391, 9 bits
            int c  = ei[N_EDGE + e];      // < 100000, 17 bits
            float w = ea[e];
            int lofs = atomicAdd(&hist[b], 1);
            int pos  = segb[b] + lofs;
            if (pos < CAP)
                bucket[(size_t)b * CAP + pos] =
                    make_int2((rl << 17) | c, __float_as_int(w));
        }
    }
}

// ---------------------------------------------------------------------------
// 2. exclusive scan of NB bucket counts -> CSR bucket bases; a[L]=tanh(alpha)
__global__ void bucket_scan_kernel(const int* __restrict__ bucket_cursor,
                                   int* __restrict__ bucket_base,
                                   const float* __restrict__ alphas,
                                   float* __restrict__ a_vals) {
    __shared__ int sc[NB];
    int tid = threadIdx.x;               // 256 threads
    int v = bucket_cursor[tid];
    sc[tid] = v;
    __syncthreads();
    for (int off = 1; off < NB; off <<= 1) {
        int t = (tid >= off) ? sc[tid - off] : 0;
        __syncthreads();
        sc[tid] += t;
        __syncthreads();
    }
    bucket_base[tid] = sc[tid] - v;      // exclusive
    if (tid < DEPTH + 1) a_vals[tid] = tanhf(alphas[tid]);
}

// ---------------------------------------------------------------------------
// 3. fused per-bucket CSR build: counts + weighted degree (LDS atomics),
//    block scan -> row_ptr/row_end/dinv, then place edges (c, raw w) at exact
//    CSR offsets in a 64KB LDS staging buffer and stream out coalesced.
//    csr keeps RAW w; dinv scaling is folded into the spmm epilogues
//    (g[c] = dinv_c*h[c] identity), so no cross-bucket dependency exists.
__global__ __launch_bounds__(1024) void stage2_fused(
        const int2* __restrict__ bucket, const int* __restrict__ bucket_cnt,
        const int* __restrict__ bucket_base,
        int* __restrict__ row_ptr, int* __restrict__ row_end,
        float* __restrict__ dinv, int2* __restrict__ csr) {
    __shared__ int          rcnt[RPB];
    __shared__ unsigned int wdeg[RPB];
    __shared__ int          sc[512];
    __shared__ int          lcur[RPB];
    __shared__ int2         staged[CAP];     // 64 KB
    int b = blockIdx.x, tid = threadIdx.x;

    for (int i = tid; i < RPB; i += 1024) { rcnt[i] = 0; wdeg[i] = 0u; }
    __syncthreads();

    int cnt = bucket_cnt[b];
    const int2* src = bucket + (size_t)b * CAP;
    for (int i = tid; i < cnt; i += 1024) {
        int2 e = src[i];
        int rl = e.x >> 17;
        float w = __int_as_float(e.y);
        atomicAdd(&rcnt[rl], 1);
        atomicAdd(&wdeg[rl], (unsigned int)(w * DEG_SCALE + 0.5f));
    }
    __syncthreads();

    // inclusive scan over 512 (RPB padded); all threads hit the barriers
    int v = 0;
    if (tid < 512) { v = (tid < RPB) ? rcnt[tid] : 0; sc[tid] = v; }
    __syncthreads();
    for (int off = 1; off < 512; off <<= 1) {
        int t = 0;
        if (tid < 512 && tid >= off) t = sc[tid - off];
        __syncthreads();
        if (tid < 512) sc[tid] += t;
        __syncthreads();
    }

    int base_b = bucket_base[b];
    if (tid < RPB) {
        int excl = sc[tid] - v;
        lcur[tid] = excl;
        int row = b * RPB + tid;
        if (row < N_NODE) {
            row_ptr[row] = base_b + excl;
            row_end[row] = base_b + excl + rcnt[tid];
            float d = (float)wdeg[tid] * (1.0f / DEG_SCALE);
            dinv[row] = (d > 0.0f) ? rsqrtf(d) : 0.0f;
        }
    }
    __syncthreads();

    for (int i = tid; i < cnt; i += 1024) {
        int2 e = src[i];                   // second read: L2-hot 64KB slice
        int rl = e.x >> 17;
        int c  = e.x & 0x1FFFF;
        int pos = atomicAdd(&lcur[rl], 1);
        staged[pos] = make_int2(c, e.y);   // keep raw w
    }
    __syncthreads();

    for (int i = tid; i < cnt; i += 1024) csr[base_b + i] = staged[i];
}

// ---------------------------------------------------------------------------
// 4. out[n,0,d] = x[n,d] (exact); bf16 shadow hb0 = bf16(dinv[n]*x[n])
__global__ void init_out_kernel(const float* __restrict__ x,
                                const float* __restrict__ dinv,
                                float* __restrict__ out,
                                unsigned short* __restrict__ hb0,
                                int write_hb) {
    int i = blockIdx.x * blockDim.x + threadIdx.x;   // one per 4 feats
    if (i < N_NODE * (D_FEAT / 4)) {
        int n  = i >> 4;
        int d4 = (i & 15) << 2;
        float4 v = *(const float4*)&x[(size_t)n * D_FEAT + d4];
        *(float4*)&out[(size_t)n * OUT_STRIDE + d4] = v;
        if (write_hb) {
            float s = dinv[n];
            uint2 o;
            o.x = bf16_rne(v.x * s) | (bf16_rne(v.y * s) << 16);
            o.y = bf16_rne(v.z * s) | (bf16_rne(v.w * s) << 16);
            *(uint2*)&hb0[(size_t)n * D_FEAT + d4] = o;
        }
    }
}

// ---------------------------------------------------------------------------
// 5a. gather SpMM, bf16 dinv-scaled source: wave = node;
//     8 edge-subgroups x 8 lanes x 8 feats (uint4 row loads).
//     out_L[i] = aL*dinv_i * sum w_e*g[col_e];  g_L[i] = dinv_i*out_L[i]
__global__ void spmm_bf16_kernel(const int* __restrict__ row_ptr,
                                 const int* __restrict__ row_end,
                                 const int2* __restrict__ csr,
                                 const float* __restrict__ a_vals,
                                 const float* __restrict__ dinv,
                                 const unsigned short* __restrict__ hsrc,
                                 unsigned short* __restrict__ hdst,
                                 float* __restrict__ out,
                                 int L, int write_hdst) {
    int node = blockIdx.x * (blockDim.x >> 6) + (threadIdx.x >> 6);
    int lane = threadIdx.x & 63;
    if (node >= N_NODE) return;
    int beg = row_ptr[node];
    int end = row_end[node];
    int g = lane >> 3;        // edge subgroup 0..7
    int q = lane & 7;         // 8-feature slot

    float acc[8] = {0, 0, 0, 0, 0, 0, 0, 0};

    for (int chunk = beg; chunk < end; chunk += 64) {
        int idx = chunk + lane;
        int2 pv = (idx < end) ? csr[idx] : make_int2(0, 0);
        int navail = end - chunk;
        if (navail > 64) navail = 64;
        for (int t = 0; t < navail; t += 8) {
            int sub = t + g;
            int   cc = __shfl(pv.x, sub);
            float vv = __int_as_float(__shfl(pv.y, sub));
            bool valid = (sub < navail);
            int   c_safe = valid ? cc : 0;
            float v_safe = valid ? vv : 0.0f;
            uint4 hv = *(const uint4*)&hsrc[(size_t)c_safe * D_FEAT + (q << 3)];
            acc[0] += v_safe * __uint_as_float((hv.x & 0xFFFFu) << 16);
            acc[1] += v_safe * __uint_as_float(hv.x & 0xFFFF0000u);
            acc[2] += v_safe * __uint_as_float((hv.y & 0xFFFFu) << 16);
            acc[3] += v_safe * __uint_as_float(hv.y & 0xFFFF0000u);
            acc[4] += v_safe * __uint_as_float((hv.z & 0xFFFFu) << 16);
            acc[5] += v_safe * __uint_as_float(hv.z & 0xFFFF0000u);
            acc[6] += v_safe * __uint_as_float((hv.w & 0xFFFFu) << 16);
            acc[7] += v_safe * __uint_as_float(hv.w & 0xFFFF0000u);
        }
    }

    #pragma unroll
    for (int j = 0; j < 8; ++j) {
        acc[j] += __shfl_down(acc[j], 32);
        acc[j] += __shfl_down(acc[j], 16);
        acc[j] += __shfl_down(acc[j], 8);
    }

    if (g == 0) {
        float di = dinv[node];
        float aL = a_vals[L];
        float s1 = aL * di;          // out scale
        float s2 = s1 * di;          // next-shadow scale
        float4 r0 = make_float4(s1 * acc[0], s1 * acc[1],
                                s1 * acc[2], s1 * acc[3]);
        float4 r1 = make_float4(s1 * acc[4], s1 * acc[5],
                                s1 * acc[6], s1 * acc[7]);
        size_t ob = (size_t)node * OUT_STRIDE + L * D_FEAT + (q << 3);
        *(float4*)&out[ob]     = r0;
        *(float4*)&out[ob + 4] = r1;
        if (write_hdst) {
            uint4 o;
            o.x = bf16_rne(s2 * acc[0]) | (bf16_rne(s2 * acc[1]) << 16);
            o.y = bf16_rne(s2 * acc[2]) | (bf16_rne(s2 * acc[3]) << 16);
            o.z = bf16_rne(s2 * acc[4]) | (bf16_rne(s2 * acc[5]) << 16);
            o.w = bf16_rne(s2 * acc[6]) | (bf16_rne(s2 * acc[7]) << 16);
            *(uint4*)&hdst[(size_t)node * D_FEAT + (q << 3)] = o;
        }
    }
}

// 5b. fallback fp32-source gather (used only if ws too small for shadows).
//     csr holds raw w -> needs dinv[c] gather + dinv_i epilogue scale.
__global__ void spmm_f32_kernel(const int* __restrict__ row_ptr,
                                const int* __restrict__ row_end,
                                const int2* __restrict__ csr,
                                const float* __restrict__ a_vals,
                                const float* __restrict__ dinv,
                                float* __restrict__ out,
                                int L) {
    int node = blockIdx.x * (blockDim.x >> 6) + (threadIdx.x >> 6);
    int lane = threadIdx.x & 63;
    if (node >= N_NODE) return;
    int beg = row_ptr[node];
    int end = row_end[node];
    int g = lane >> 4;
    int q = lane & 15;
    int src_base = (L - 1) * D_FEAT + (q << 2);

    float4 acc = make_float4(0.0f, 0.0f, 0.0f, 0.0f);
    for (int chunk = beg; chunk < end; chunk += 64) {
        int idx = chunk + lane;
        int2 pv = (idx < end) ? csr[idx] : make_int2(0, 0);
        int navail = end - chunk;
        if (navail > 64) navail = 64;
        for (int t = 0; t < navail; t += 4) {
            int sub = t + g;
            int   cc = __shfl(pv.x, sub);
            float vv = __int_as_float(__shfl(pv.y, sub));
            bool valid = (sub < navail);
            int   c_safe = valid ? cc : 0;
            float v_safe = valid ? (vv * dinv[c_safe]) : 0.0f;
            const float4 hv =
                *(const float4*)&out[(size_t)c_safe * OUT_STRIDE + src_base];
            acc.x += v_safe * hv.x;
            acc.y += v_safe * hv.y;
            acc.z += v_safe * hv.z;
            acc.w += v_safe * hv.w;
        }
    }
    acc.x += __shfl_down(acc.x, 32);
    acc.y += __shfl_down(acc.y, 32);
    acc.z += __shfl_down(acc.z, 32);
    acc.w += __shfl_down(acc.w, 32);
    acc.x += __shfl_down(acc.x, 16);
    acc.y += __shfl_down(acc.y, 16);
    acc.z += __shfl_down(acc.z, 16);
    acc.w += __shfl_down(acc.w, 16);
    if (g == 0) {
        float s1 = a_vals[L] * dinv[node];
        float4 r = make_float4(s1 * acc.x, s1 * acc.y, s1 * acc.z, s1 * acc.w);
        *(float4*)&out[(size_t)node * OUT_STRIDE + L * D_FEAT + (q << 2)] = r;
    }
}

// ---------------------------------------------------------------------------
extern "C" void kernel_launch(void* const* d_in, const int* in_sizes, int n_in,
                              void* d_out, int out_size, void* d_ws, size_t ws_size,
                              hipStream_t stream) {
    const float* x      = (const float*)d_in[0];
    const int*   ei     = (const int*)d_in[1];   // [2, E] int32
    const float* ea     = (const float*)d_in[2];
    const float* alphas = (const float*)d_in[3];
    float*       out    = (float*)d_out;

    // workspace layout (bucket store aliases the bf16 shadows: bucket data is
    // dead before init_out runs)
    int2*  csr          = (int2*)d_ws;                       // E     (12.8 MB)
    int*   row_ptr      = (int*)(csr + N_EDGE);              // N
    int*   row_end      = row_ptr + N_NODE;                  // N
    float* dinv         = (float*)(row_end + N_NODE);        // N
    int*   bucket_cursor= (int*)(dinv + N_NODE);             // NB
    int*   bucket_base  = bucket_cursor + NB;                // NB
    float* a_vals       = (float*)(bucket_base + NB);        // 4
    int2*  bucket       = (int2*)(a_vals + 4);               // NB*CAP (16.8 MB)
    unsigned short* hb0 = (unsigned short*)bucket;           // union w/ bucket
    unsigned short* hb1 = hb0 + (size_t)N_NODE * D_FEAT;

    size_t base_bytes = (size_t)((char*)bucket - (char*)d_ws);
    size_t need_bf16  = base_bytes +
        2 * (size_t)N_NODE * D_FEAT * sizeof(unsigned short);   // ~39.7 MB
    int use_bf16 = (ws_size >= need_bf16) ? 1 : 0;

    hipMemsetAsync(bucket_cursor, 0, NB * sizeof(int), stream);

    stage1_bucket<<<S1_BLOCKS, S1_BS, 0, stream>>>(ei, ea, bucket_cursor, bucket);
    bucket_scan_kernel<<<1, NB, 0, stream>>>(bucket_cursor, bucket_base,
                                             alphas, a_vals);
    stage2_fused<<<NB, 1024, 0, stream>>>(bucket, bucket_cursor, bucket_base,
                                          row_ptr, row_end, dinv, csr);
    init_out_kernel<<<(N_NODE * (D_FEAT / 4) + 255) / 256, 256, 0, stream>>>(
        x, dinv, out, hb0, use_bf16);

    int nodes_per_block = 256 / 64;
    int spmm_blocks = (N_NODE + nodes_per_block - 1) / nodes_per_block;
    if (use_bf16) {
        // L=1: src hb0 -> dst hb1 ; L=2: src hb1 -> dst hb0 ; L=3: src hb0, no dst
        spmm_bf16_kernel<<<spmm_blocks, 256, 0, stream>>>(row_ptr, row_end, csr,
            a_vals, dinv, hb0, hb1, out, 1, 1);
        spmm_bf16_kernel<<<spmm_blocks, 256, 0, stream>>>(row_ptr, row_end, csr,
            a_vals, dinv, hb1, hb0, out, 2, 1);
        spmm_bf16_kernel<<<spmm_blocks, 256, 0, stream>>>(row_ptr, row_end, csr,
            a_vals, dinv, hb0, hb1, out, 3, 0);
    } else {
        for (int L = 1; L <= DEPTH; ++L) {
            spmm_f32_kernel<<<spmm_blocks, 256, 0, stream>>>(row_ptr, row_end, csr,
                a_vals, dinv, out, L);
        }
    }
}